// Round 1
// baseline (2123.511 us; speedup 1.0000x reference)
//
#include <hip/hip_runtime.h>

typedef unsigned short u16;
typedef __attribute__((ext_vector_type(8))) short s16x8;
typedef __attribute__((ext_vector_type(4))) short s16x4;
typedef __attribute__((ext_vector_type(4))) float f32x4;

#define DEVI __device__ __forceinline__

DEVI u16 f2b(float f) {
  union { float f; unsigned u; } v; v.f = f;
  unsigned r = v.u + 0x7FFFu + ((v.u >> 16) & 1u);
  return (u16)(r >> 16);
}
DEVI float b2f(u16 h) {
  union { unsigned u; float f; } v; v.u = ((unsigned)h) << 16;
  return v.f;
}

DEVI s16x4 cvt4(const float* p) {
  float4 v = *(const float4*)p;
  s16x4 r;
  r.x = (short)f2b(v.x); r.y = (short)f2b(v.y);
  r.z = (short)f2b(v.z); r.w = (short)f2b(v.w);
  return r;
}
DEVI s16x4 cvt4(const u16* p) { return *(const s16x4*)p; }

DEVI void store_c(u16* p, float v) { *p = f2b(v); }
DEVI void store_c(float* p, float v) { *p = v; }

// C[M][N] = A[M][K] @ Bw[K][N], bf16 MFMA, fp32 accum.
template <typename TA, typename TC>
__global__ void gemm_bf16(const TA* __restrict__ A, const float* __restrict__ Bw,
                          TC* __restrict__ C, int M, int N, int K) {
  __shared__ __attribute__((aligned(16))) u16 As[128][72];  // [m][k], row 144B
  __shared__ __attribute__((aligned(16))) u16 Bs[128][72];  // [n][k]
  const int t = threadIdx.x;
  const int row0 = blockIdx.y * 128;
  const int col0 = blockIdx.x * 128;
  const int w = t >> 6, lane = t & 63;
  const int lc = lane & 15, lg = lane >> 4;
  const int wm = (w >> 1) * 64, wn = (w & 1) * 64;

  const f32x4 FZ = {0.f, 0.f, 0.f, 0.f};
  f32x4 acc[4][4];
#pragma unroll
  for (int i = 0; i < 4; ++i)
#pragma unroll
    for (int j = 0; j < 4; ++j) acc[i][j] = FZ;

  const int a_slot = t & 15, a_r0 = t >> 4;
  const int b_n4 = t & 31, b_k40 = t >> 5;

  for (int k0 = 0; k0 < K; k0 += 64) {
    __syncthreads();
    // stage A tile [128][64]
#pragma unroll
    for (int i = 0; i < 8; ++i) {
      int r = a_r0 + 16 * i;
      *(s16x4*)&As[r][a_slot * 4] = cvt4(A + (size_t)(row0 + r) * K + k0 + a_slot * 4);
    }
    // stage B tile transposed -> Bs[n][k]
#pragma unroll
    for (int rep = 0; rep < 2; ++rep) {
      int k4 = b_k40 + 8 * rep;
      const float* src = Bw + (size_t)(k0 + k4 * 4) * N + col0 + b_n4 * 4;
      float4 r0 = *(const float4*)src;
      float4 r1 = *(const float4*)(src + N);
      float4 r2 = *(const float4*)(src + 2 * (size_t)N);
      float4 r3 = *(const float4*)(src + 3 * (size_t)N);
      s16x4 c0 = {(short)f2b(r0.x), (short)f2b(r1.x), (short)f2b(r2.x), (short)f2b(r3.x)};
      s16x4 c1 = {(short)f2b(r0.y), (short)f2b(r1.y), (short)f2b(r2.y), (short)f2b(r3.y)};
      s16x4 c2 = {(short)f2b(r0.z), (short)f2b(r1.z), (short)f2b(r2.z), (short)f2b(r3.z)};
      s16x4 c3 = {(short)f2b(r0.w), (short)f2b(r1.w), (short)f2b(r2.w), (short)f2b(r3.w)};
      *(s16x4*)&Bs[b_n4 * 4 + 0][k4 * 4] = c0;
      *(s16x4*)&Bs[b_n4 * 4 + 1][k4 * 4] = c1;
      *(s16x4*)&Bs[b_n4 * 4 + 2][k4 * 4] = c2;
      *(s16x4*)&Bs[b_n4 * 4 + 3][k4 * 4] = c3;
    }
    __syncthreads();
#pragma unroll
    for (int ks = 0; ks < 2; ++ks) {
      s16x8 af[4], bfr[4];
#pragma unroll
      for (int mf = 0; mf < 4; ++mf)
        af[mf] = *(const s16x8*)&As[wm + mf * 16 + lc][ks * 32 + lg * 8];
#pragma unroll
      for (int nf = 0; nf < 4; ++nf)
        bfr[nf] = *(const s16x8*)&Bs[wn + nf * 16 + lc][ks * 32 + lg * 8];
#pragma unroll
      for (int mf = 0; mf < 4; ++mf)
#pragma unroll
        for (int nf = 0; nf < 4; ++nf)
          acc[mf][nf] = __builtin_amdgcn_mfma_f32_16x16x32_bf16(af[mf], bfr[nf], acc[mf][nf], 0, 0, 0);
    }
  }
#pragma unroll
  for (int mf = 0; mf < 4; ++mf)
#pragma unroll
    for (int nf = 0; nf < 4; ++nf)
#pragma unroll
      for (int r = 0; r < 4; ++r) {
        int rg = row0 + wm + mf * 16 + lg * 4 + r;
        int cg = col0 + wn + nf * 16 + lc;
        store_c(&C[(size_t)rg * N + cg], acc[mf][nf][r]);
      }
}

// qkv[b][s][6144]: q 32 heads, k 8 heads (rope both), layout out: [b][head][s][128]
__global__ void rope_kernel(const u16* __restrict__ qkv, const float* __restrict__ cosb,
                            const float* __restrict__ sinb, u16* __restrict__ q_r,
                            u16* __restrict__ k_r) {
  const int bs = blockIdx.x;
  const int b = bs >> 11, s = bs & 2047;
  const u16* row = qkv + (size_t)bs * 6144;
  for (int p = threadIdx.x; p < 2560; p += 256) {
    int head = p >> 6, d = p & 63;
    float c0 = cosb[s * 128 + d], s0 = sinb[s * 128 + d];
    float x1 = b2f(row[head * 128 + d]);
    float x2 = b2f(row[head * 128 + d + 64]);
    float o1 = x1 * c0 - x2 * s0;  // out[d]   = x1*cos - x2*sin
    float o2 = x2 * c0 + x1 * s0;  // out[d+64]= x2*cos + x1*sin
    if (head < 32) {
      size_t idx = ((size_t)(b * 32 + head) * 2048 + s) * 128 + d;
      q_r[idx] = f2b(o1);
      q_r[idx + 64] = f2b(o2);
    } else {
      size_t idx = ((size_t)(b * 8 + (head - 32)) * 2048 + s) * 128 + d;
      k_r[idx] = f2b(o1);
      k_r[idx + 64] = f2b(o2);
    }
  }
}

// v_t[b][kvh][d][s] = qkv[b][s][5120 + kvh*128 + d]
__global__ void vtrans_kernel(const u16* __restrict__ qkv, u16* __restrict__ v_t) {
  __shared__ __attribute__((aligned(16))) u16 tile[64][72];
  const int t = threadIdx.x;
  const int s0 = blockIdx.x * 64;
  const int d0 = blockIdx.y * 64;
  const int bk = blockIdx.z;  // b*8+kvh
  const int b = bk >> 3, kvh = bk & 7;
  const int slot = t & 7, r0 = t >> 3;
#pragma unroll
  for (int i = 0; i < 2; ++i) {
    int s_ = r0 + 32 * i;
    *(s16x8*)&tile[s_][slot * 8] =
        *(const s16x8*)(qkv + (size_t)(b * 2048 + s0 + s_) * 6144 + 5120 + kvh * 128 + d0 + slot * 8);
  }
  __syncthreads();
#pragma unroll
  for (int i = 0; i < 2; ++i) {
    int d_ = r0 + 32 * i;
    s16x8 v;
#pragma unroll
    for (int j = 0; j < 8; ++j) v[j] = (short)tile[slot * 8 + j][d_];
    *(s16x8*)(v_t + ((size_t)bk * 128 + d0 + d_) * 2048 + s0 + slot * 8) = v;
  }
}

// Flash causal attention. Block = (qtile 128, head, batch). 4 waves x 32 q-rows.
__global__ void attn_kernel(const u16* __restrict__ q_r, const u16* __restrict__ k_r,
                            const u16* __restrict__ v_t, u16* __restrict__ attn) {
  __shared__ __attribute__((aligned(16))) u16 Ks[64][136];    // [s][d]
  __shared__ __attribute__((aligned(16))) u16 Vs[128][72];    // [d][s]
  __shared__ __attribute__((aligned(16))) u16 Ps[4][32][72];  // per-wave [q][s]
  const int t = threadIdx.x;
  const int q0 = blockIdx.x * 128;
  const int h = blockIdx.y;
  const int b = blockIdx.z;
  const int kvh = h >> 2;
  const int w = t >> 6, lane = t & 63, lc = lane & 15, lg = lane >> 4;
  const int qw = q0 + w * 32;

  const u16* qbase = q_r + (size_t)(b * 32 + h) * 2048 * 128;
  const u16* kbase = k_r + (size_t)(b * 8 + kvh) * 2048 * 128;
  const u16* vbase = v_t + (size_t)(b * 8 + kvh) * 128 * 2048;

  s16x8 qf[2][4];
#pragma unroll
  for (int mf = 0; mf < 2; ++mf)
#pragma unroll
    for (int ks = 0; ks < 4; ++ks)
      qf[mf][ks] = *(const s16x8*)(qbase + (size_t)(qw + mf * 16 + lc) * 128 + ks * 32 + lg * 8);

  const f32x4 FZ = {0.f, 0.f, 0.f, 0.f};
  f32x4 o_acc[2][8];
  float m_run[2][4], l_run[2][4];
#pragma unroll
  for (int mf = 0; mf < 2; ++mf) {
#pragma unroll
    for (int nf = 0; nf < 8; ++nf) o_acc[mf][nf] = FZ;
#pragma unroll
    for (int r = 0; r < 4; ++r) { m_run[mf][r] = -3e38f; l_run[mf][r] = 0.f; }
  }
  const float scale2 = 0.08838834764831845f * 1.44269504088896340736f;  // 1/sqrt(128)*log2(e)

  const int ntiles = q0 / 64 + 2;
  for (int kt = 0; kt < ntiles; ++kt) {
    const int k0 = kt * 64;
    __syncthreads();
    {  // stage K [64][128]
      int slot = t & 15, sr = t >> 4;
#pragma unroll
      for (int i = 0; i < 4; ++i) {
        int s_ = sr + 16 * i;
        *(s16x8*)&Ks[s_][slot * 8] = *(const s16x8*)(kbase + (size_t)(k0 + s_) * 128 + slot * 8);
      }
    }
    {  // stage V^T [128][64]
      int slot = t & 7, dr = t >> 3;
#pragma unroll
      for (int i = 0; i < 4; ++i) {
        int d_ = dr + 32 * i;
        *(s16x8*)&Vs[d_][slot * 8] = *(const s16x8*)(vbase + (size_t)d_ * 2048 + k0 + slot * 8);
      }
    }
    __syncthreads();
    // S = Q K^T
    f32x4 sacc[2][4];
#pragma unroll
    for (int mf = 0; mf < 2; ++mf)
#pragma unroll
      for (int nf = 0; nf < 4; ++nf) sacc[mf][nf] = FZ;
#pragma unroll
    for (int ks = 0; ks < 4; ++ks) {
      s16x8 kf[4];
#pragma unroll
      for (int nf = 0; nf < 4; ++nf)
        kf[nf] = *(const s16x8*)&Ks[nf * 16 + lc][ks * 32 + lg * 8];
#pragma unroll
      for (int mf = 0; mf < 2; ++mf)
#pragma unroll
        for (int nf = 0; nf < 4; ++nf)
          sacc[mf][nf] = __builtin_amdgcn_mfma_f32_16x16x32_bf16(qf[mf][ks], kf[nf], sacc[mf][nf], 0, 0, 0);
    }
    // online softmax (exp2 domain)
#pragma unroll
    for (int mf = 0; mf < 2; ++mf) {
      float pm[4] = {-3e38f, -3e38f, -3e38f, -3e38f};
#pragma unroll
      for (int nf = 0; nf < 4; ++nf) {
        int kv = k0 + nf * 16 + lc;
#pragma unroll
        for (int r = 0; r < 4; ++r) {
          int qg = qw + mf * 16 + lg * 4 + r;
          float sv = sacc[mf][nf][r] * scale2;
          sv = (kv <= qg) ? sv : -3e38f;
          sacc[mf][nf][r] = sv;
          pm[r] = fmaxf(pm[r], sv);
        }
      }
#pragma unroll
      for (int r = 0; r < 4; ++r) {
        pm[r] = fmaxf(pm[r], __shfl_xor(pm[r], 1));
        pm[r] = fmaxf(pm[r], __shfl_xor(pm[r], 2));
        pm[r] = fmaxf(pm[r], __shfl_xor(pm[r], 4));
        pm[r] = fmaxf(pm[r], __shfl_xor(pm[r], 8));
      }
      float psum[4] = {0.f, 0.f, 0.f, 0.f};
#pragma unroll
      for (int r = 0; r < 4; ++r) {
        float mnew = fmaxf(m_run[mf][r], pm[r]);
        float f = exp2f(m_run[mf][r] - mnew);
        m_run[mf][r] = mnew;
        l_run[mf][r] *= f;
#pragma unroll
        for (int nf = 0; nf < 8; ++nf) o_acc[mf][nf][r] *= f;
      }
#pragma unroll
      for (int nf = 0; nf < 4; ++nf)
#pragma unroll
        for (int r = 0; r < 4; ++r) {
          float p = exp2f(sacc[mf][nf][r] - m_run[mf][r]);
          psum[r] += p;
          Ps[w][mf * 16 + lg * 4 + r][nf * 16 + lc] = f2b(p);
        }
#pragma unroll
      for (int r = 0; r < 4; ++r) {
        float ps = psum[r];
        ps += __shfl_xor(ps, 1);
        ps += __shfl_xor(ps, 2);
        ps += __shfl_xor(ps, 4);
        ps += __shfl_xor(ps, 8);
        l_run[mf][r] += ps;
      }
    }
    // O += P V
#pragma unroll
    for (int ks = 0; ks < 2; ++ks) {
      s16x8 pf[2];
#pragma unroll
      for (int mf = 0; mf < 2; ++mf)
        pf[mf] = *(const s16x8*)&Ps[w][mf * 16 + lc][ks * 32 + lg * 8];
#pragma unroll
      for (int nf = 0; nf < 8; ++nf) {
        s16x8 vf = *(const s16x8*)&Vs[nf * 16 + lc][ks * 32 + lg * 8];
#pragma unroll
        for (int mf = 0; mf < 2; ++mf)
          o_acc[mf][nf] = __builtin_amdgcn_mfma_f32_16x16x32_bf16(pf[mf], vf, o_acc[mf][nf], 0, 0, 0);
      }
    }
  }
  // epilogue: O/l -> attn[b][q][h*128+d] (bf16)
#pragma unroll
  for (int mf = 0; mf < 2; ++mf)
#pragma unroll
    for (int r = 0; r < 4; ++r) {
      float inv = 1.0f / l_run[mf][r];
      int qg = qw + mf * 16 + lg * 4 + r;
#pragma unroll
      for (int nf = 0; nf < 8; ++nf)
        attn[(size_t)(b * 2048 + qg) * 4096 + h * 128 + nf * 16 + lc] =
            f2b(o_acc[mf][nf][r] * inv);
    }
}

extern "C" void kernel_launch(void* const* d_in, const int* in_sizes, int n_in,
                              void* d_out, int out_size, void* d_ws, size_t ws_size,
                              hipStream_t stream) {
  (void)in_sizes; (void)n_in; (void)out_size; (void)ws_size;
  const float* x = (const float*)d_in[0];
  const float* cosb = (const float*)d_in[1];
  const float* sinb = (const float*)d_in[2];
  const float* Wqkv = (const float*)d_in[3];
  const float* Wout = (const float*)d_in[4];
  float* out = (float*)d_out;
  char* ws = (char*)d_ws;

  u16* qkv  = (u16*)(ws);                       // 4096*6144*2   = 50,331,648
  u16* q_r  = (u16*)(ws + 50331648);            // 33,554,432
  u16* k_r  = (u16*)(ws + 83886080);            //  8,388,608
  u16* v_t  = (u16*)(ws + 92274688);            //  8,388,608
  u16* attn = (u16*)(ws + 100663296);           // 33,554,432  (end 134,217,728)

  gemm_bf16<float, u16><<<dim3(48, 32), 256, 0, stream>>>(x, Wqkv, qkv, 4096, 6144, 4096);
  rope_kernel<<<4096, 256, 0, stream>>>(qkv, cosb, sinb, q_r, k_r);
  vtrans_kernel<<<dim3(32, 2, 16), 256, 0, stream>>>(qkv, v_t);
  attn_kernel<<<dim3(16, 32, 2), 256, 0, stream>>>(q_r, k_r, v_t, attn);
  gemm_bf16<u16, float><<<dim3(32, 32), 256, 0, stream>>>(attn, Wout, out, 4096, 4096, 4096);
}

// Round 2
// 786.589 us; speedup vs baseline: 2.6996x; 2.6996x over previous
//
#include <hip/hip_runtime.h>

typedef unsigned short u16;
typedef __attribute__((ext_vector_type(8))) short s16x8;
typedef __attribute__((ext_vector_type(4))) short s16x4;
typedef __attribute__((ext_vector_type(4))) float f32x4;

#define DEVI __device__ __forceinline__

DEVI u16 f2b(float f) {
  union { float f; unsigned u; } v; v.f = f;
  unsigned r = v.u + 0x7FFFu + ((v.u >> 16) & 1u);
  return (u16)(r >> 16);
}
DEVI float b2f(u16 h) {
  union { unsigned u; float f; } v; v.u = ((unsigned)h) << 16;
  return v.f;
}

typedef const __attribute__((address_space(1))) void gas_void;
typedef __attribute__((address_space(3))) void las_void;
DEVI void gload16(const void* g, void* l) {
  __builtin_amdgcn_global_load_lds((gas_void*)g, (las_void*)l, 16, 0, 0);
}

// W [K][N] f32 -> Wt [N][K] bf16 (64x64 tiles)
__global__ void trans_bf16(const float* __restrict__ W, u16* __restrict__ Wt, int K, int N) {
  __shared__ __attribute__((aligned(16))) u16 tile[64][68];
  const int t = threadIdx.x;
  const int n0 = blockIdx.x * 64, k0 = blockIdx.y * 64;
#pragma unroll
  for (int i = 0; i < 4; ++i) {
    int c = i * 256 + t;
    int r = c >> 4, q = c & 15;
    float4 v = *(const float4*)(W + (size_t)(k0 + r) * N + n0 + q * 4);
    s16x4 o = {(short)f2b(v.x), (short)f2b(v.y), (short)f2b(v.z), (short)f2b(v.w)};
    *(s16x4*)&tile[r][q * 4] = o;
  }
  __syncthreads();
#pragma unroll
  for (int i = 0; i < 2; ++i) {
    int c = i * 256 + t;
    int n_ = c >> 3, ck = (c & 7) * 8;
    s16x8 o;
#pragma unroll
    for (int j = 0; j < 8; ++j) o[j] = (short)tile[ck + j][n_];
    *(s16x8*)(Wt + (size_t)(n0 + n_) * K + k0 + ck) = o;
  }
}

// C[M][N] = A[M][K] @ Bt[N][K]^T. Bt staged via global_load_lds; A either f32
// (reg-convert) or bf16 (global_load_lds).
template <bool AF32, typename TC>
__global__ void __launch_bounds__(256) gemm_kernel(const void* __restrict__ Av,
                                                   const u16* __restrict__ Bt,
                                                   TC* __restrict__ C, int M, int N, int K) {
  __shared__ __attribute__((aligned(16))) u16 As[128 * 64];
  __shared__ __attribute__((aligned(16))) u16 Bs[128 * 64];
  const int t = threadIdx.x;
  const int col0 = blockIdx.x * 128, row0 = blockIdx.y * 128;
  const int w = t >> 6, lane = t & 63, lc = lane & 15, lg = lane >> 4;
  const int wm = (w >> 1) * 64, wn = (w & 1) * 64;
  const f32x4 FZ = {0.f, 0.f, 0.f, 0.f};
  f32x4 acc[4][4];
#pragma unroll
  for (int i = 0; i < 4; ++i)
#pragma unroll
    for (int j = 0; j < 4; ++j) acc[i][j] = FZ;

  for (int k0 = 0; k0 < K; k0 += 64) {
    __syncthreads();
#pragma unroll
    for (int i = 0; i < 4; ++i) {
      int c = i * 256 + t;
      gload16(Bt + (size_t)(col0 + (c >> 3)) * K + k0 + (c & 7) * 8, &Bs[c * 8]);
    }
    if constexpr (AF32) {
      const float* A = (const float*)Av;
#pragma unroll
      for (int i = 0; i < 4; ++i) {
        int c = i * 256 + t;
        int r = c >> 3, cb = (c & 7) * 8;
        const float* p = A + (size_t)(row0 + r) * K + k0 + cb;
        float4 u = *(const float4*)p;
        float4 v = *(const float4*)(p + 4);
        s16x8 o = {(short)f2b(u.x), (short)f2b(u.y), (short)f2b(u.z), (short)f2b(u.w),
                   (short)f2b(v.x), (short)f2b(v.y), (short)f2b(v.z), (short)f2b(v.w)};
        *(s16x8*)&As[r * 64 + cb] = o;
      }
    } else {
      const u16* A = (const u16*)Av;
#pragma unroll
      for (int i = 0; i < 4; ++i) {
        int c = i * 256 + t;
        gload16(A + (size_t)(row0 + (c >> 3)) * K + k0 + (c & 7) * 8, &As[c * 8]);
      }
    }
    __syncthreads();
#pragma unroll
    for (int ks = 0; ks < 2; ++ks) {
      s16x8 af[4], bfv[4];
#pragma unroll
      for (int mf = 0; mf < 4; ++mf)
        af[mf] = *(const s16x8*)&As[(wm + mf * 16 + lc) * 64 + ks * 32 + lg * 8];
#pragma unroll
      for (int nf = 0; nf < 4; ++nf)
        bfv[nf] = *(const s16x8*)&Bs[(wn + nf * 16 + lc) * 64 + ks * 32 + lg * 8];
#pragma unroll
      for (int mf = 0; mf < 4; ++mf)
#pragma unroll
        for (int nf = 0; nf < 4; ++nf)
          acc[mf][nf] = __builtin_amdgcn_mfma_f32_16x16x32_bf16(af[mf], bfv[nf], acc[mf][nf], 0, 0, 0);
    }
  }
#pragma unroll
  for (int mf = 0; mf < 4; ++mf)
#pragma unroll
    for (int nf = 0; nf < 4; ++nf)
#pragma unroll
      for (int r = 0; r < 4; ++r) {
        int rg = row0 + wm + mf * 16 + lg * 4 + r;
        int cg = col0 + wn + nf * 16 + lc;
        if constexpr (sizeof(TC) == 2)
          ((u16*)C)[(size_t)rg * N + cg] = f2b(acc[mf][nf][r]);
        else
          ((float*)C)[(size_t)rg * N + cg] = acc[mf][nf][r];
      }
}

// In-place RoPE on qkv columns [0, 5120): q heads 0..31, k heads 32..39.
__global__ void rope_kernel(u16* __restrict__ qkv, const float* __restrict__ cosb,
                            const float* __restrict__ sinb) {
  const int bs = blockIdx.x;
  const int s = bs & 2047;
  u16* row = qkv + (size_t)bs * 6144;
  const float* cr = cosb + s * 128;
  const float* sr = sinb + s * 128;
  for (int p = threadIdx.x; p < 320; p += 256) {
    int head = p >> 3, dc = (p & 7) * 8;
    int ci = head * 128 + dc;
    s16x8 a = *(const s16x8*)&row[ci];
    s16x8 bb = *(const s16x8*)&row[ci + 64];
    float4 c0 = *(const float4*)(cr + dc), c1 = *(const float4*)(cr + dc + 4);
    float4 s0 = *(const float4*)(sr + dc), s1 = *(const float4*)(sr + dc + 4);
    float cv[8] = {c0.x, c0.y, c0.z, c0.w, c1.x, c1.y, c1.z, c1.w};
    float sv[8] = {s0.x, s0.y, s0.z, s0.w, s1.x, s1.y, s1.z, s1.w};
    s16x8 o1, o2;
#pragma unroll
    for (int j = 0; j < 8; ++j) {
      float x1 = b2f((u16)a[j]), x2 = b2f((u16)bb[j]);
      o1[j] = (short)f2b(x1 * cv[j] - x2 * sv[j]);
      o2[j] = (short)f2b(x2 * cv[j] + x1 * sv[j]);
    }
    *(s16x8*)&row[ci] = o1;
    *(s16x8*)&row[ci + 64] = o2;
  }
}

// v_t[b][kvh][d][s] = qkv[b][s][5120 + kvh*128 + d]
__global__ void vtrans_kernel(const u16* __restrict__ qkv, u16* __restrict__ v_t) {
  __shared__ __attribute__((aligned(16))) u16 tile[64][72];
  const int t = threadIdx.x;
  const int s0 = blockIdx.x * 64;
  const int d0 = blockIdx.y * 64;
  const int bk = blockIdx.z;
  const int b = bk >> 3, kvh = bk & 7;
  const int slot = t & 7, r0 = t >> 3;
#pragma unroll
  for (int i = 0; i < 2; ++i) {
    int s_ = r0 + 32 * i;
    *(s16x8*)&tile[s_][slot * 8] =
        *(const s16x8*)(qkv + (size_t)(b * 2048 + s0 + s_) * 6144 + 5120 + kvh * 128 + d0 + slot * 8);
  }
  __syncthreads();
#pragma unroll
  for (int i = 0; i < 2; ++i) {
    int d_ = r0 + 32 * i;
    s16x8 v;
#pragma unroll
    for (int j = 0; j < 8; ++j) v[j] = (short)tile[slot * 8 + j][d_];
    *(s16x8*)(v_t + ((size_t)bk * 128 + d0 + d_) * 2048 + s0 + slot * 8) = v;
  }
}

// Flash causal attention; Q/K read from roped qkv; V from v_t.
// Grid = 1024 (1D), XCD-grouped (all blocks of one (b,kvh) on one XCD),
// largest q-tile first, T14 register prefetch of next K/V tile.
__global__ void __launch_bounds__(256, 2) attn_kernel(const u16* __restrict__ qkv,
                                                      const u16* __restrict__ v_t,
                                                      u16* __restrict__ attn) {
  __shared__ __attribute__((aligned(16))) u16 Ks[64][136];
  __shared__ __attribute__((aligned(16))) u16 Vs[128][72];
  __shared__ __attribute__((aligned(16))) u16 Ps[4][32][72];
  const int t = threadIdx.x;
  const int f = blockIdx.x;
  const int xcd = f & 7, ix = f >> 3;
  const int g = (xcd << 1) | (ix >> 6);   // 2 (b,kvh) groups per XCD
  const int r_ = ix & 63;
  const int b = g >> 3, kvh = g & 7;
  const int qt = 15 - (r_ >> 2);          // largest-first
  const int h = kvh * 4 + (r_ & 3);
  const int q0 = qt * 128;
  const int w = t >> 6, lane = t & 63, lc = lane & 15, lg = lane >> 4;
  const int qw = q0 + w * 32;

  const u16* qbase = qkv + (size_t)(b * 2048) * 6144 + h * 128;
  const u16* kbase = qkv + (size_t)(b * 2048) * 6144 + 4096 + kvh * 128;
  const u16* vbase = v_t + (size_t)(b * 8 + kvh) * 128 * 2048;

  s16x8 qf[2][4];
#pragma unroll
  for (int mf = 0; mf < 2; ++mf)
#pragma unroll
    for (int ks = 0; ks < 4; ++ks)
      qf[mf][ks] = *(const s16x8*)(qbase + (size_t)(qw + mf * 16 + lc) * 6144 + ks * 32 + lg * 8);

  const f32x4 FZ = {0.f, 0.f, 0.f, 0.f};
  f32x4 o_acc[2][8];
  float m_run[2][4], l_run[2][4];
#pragma unroll
  for (int mf = 0; mf < 2; ++mf) {
#pragma unroll
    for (int nf = 0; nf < 8; ++nf) o_acc[mf][nf] = FZ;
#pragma unroll
    for (int r = 0; r < 4; ++r) { m_run[mf][r] = -3e38f; l_run[mf][r] = 0.f; }
  }
  const float scale2 = 0.08838834764831845f * 1.44269504088896340736f;

  const int ntiles = q0 / 64 + 2;
  s16x8 kr[4], vr[4];
#pragma unroll
  for (int i = 0; i < 4; ++i) {
    int c = i * 256 + t;
    kr[i] = *(const s16x8*)(kbase + (size_t)(c >> 4) * 6144 + (c & 15) * 8);
    vr[i] = *(const s16x8*)(vbase + (size_t)(c >> 3) * 2048 + (c & 7) * 8);
  }

  for (int kt = 0; kt < ntiles; ++kt) {
    const int k0 = kt * 64;
    __syncthreads();
#pragma unroll
    for (int i = 0; i < 4; ++i) {
      int c = i * 256 + t;
      *(s16x8*)&Ks[c >> 4][(c & 15) * 8] = kr[i];
      *(s16x8*)&Vs[c >> 3][(c & 7) * 8] = vr[i];
    }
    __syncthreads();
    if (kt + 1 < ntiles) {  // T14: issue next-tile loads before compute
      int k1 = k0 + 64;
#pragma unroll
      for (int i = 0; i < 4; ++i) {
        int c = i * 256 + t;
        kr[i] = *(const s16x8*)(kbase + (size_t)(k1 + (c >> 4)) * 6144 + (c & 15) * 8);
        vr[i] = *(const s16x8*)(vbase + (size_t)(c >> 3) * 2048 + k1 + (c & 7) * 8);
      }
    }
    if (k0 > qw + 31) continue;  // tile fully masked for this wave

    f32x4 sacc[2][4];
#pragma unroll
    for (int mf = 0; mf < 2; ++mf)
#pragma unroll
      for (int nf = 0; nf < 4; ++nf) sacc[mf][nf] = FZ;
#pragma unroll
    for (int ks = 0; ks < 4; ++ks) {
      s16x8 kf[4];
#pragma unroll
      for (int nf = 0; nf < 4; ++nf)
        kf[nf] = *(const s16x8*)&Ks[nf * 16 + lc][ks * 32 + lg * 8];
#pragma unroll
      for (int mf = 0; mf < 2; ++mf)
#pragma unroll
        for (int nf = 0; nf < 4; ++nf)
          sacc[mf][nf] = __builtin_amdgcn_mfma_f32_16x16x32_bf16(qf[mf][ks], kf[nf], sacc[mf][nf], 0, 0, 0);
    }

#pragma unroll
    for (int mf = 0; mf < 2; ++mf) {
      float pm[4] = {-3e38f, -3e38f, -3e38f, -3e38f};
      const bool dm = (k0 + 63 > qw + mf * 16);
      if (dm) {
#pragma unroll
        for (int nf = 0; nf < 4; ++nf) {
          int kv = k0 + nf * 16 + lc;
#pragma unroll
          for (int r = 0; r < 4; ++r) {
            int qg = qw + mf * 16 + lg * 4 + r;
            float sv = sacc[mf][nf][r] * scale2;
            sv = (kv <= qg) ? sv : -3e38f;
            sacc[mf][nf][r] = sv;
            pm[r] = fmaxf(pm[r], sv);
          }
        }
      } else {
#pragma unroll
        for (int nf = 0; nf < 4; ++nf)
#pragma unroll
          for (int r = 0; r < 4; ++r) {
            float sv = sacc[mf][nf][r] * scale2;
            sacc[mf][nf][r] = sv;
            pm[r] = fmaxf(pm[r], sv);
          }
      }
#pragma unroll
      for (int r = 0; r < 4; ++r) {
        pm[r] = fmaxf(pm[r], __shfl_xor(pm[r], 1));
        pm[r] = fmaxf(pm[r], __shfl_xor(pm[r], 2));
        pm[r] = fmaxf(pm[r], __shfl_xor(pm[r], 4));
        pm[r] = fmaxf(pm[r], __shfl_xor(pm[r], 8));
      }
      bool any = false;
      float mnew[4];
#pragma unroll
      for (int r = 0; r < 4; ++r) {
        mnew[r] = fmaxf(m_run[mf][r], pm[r]);
        any |= (mnew[r] > m_run[mf][r]);
      }
      if (__any(any)) {  // defer-rescale: skip is exact when max unchanged
#pragma unroll
        for (int r = 0; r < 4; ++r) {
          float fsc = exp2f(m_run[mf][r] - mnew[r]);
          m_run[mf][r] = mnew[r];
          l_run[mf][r] *= fsc;
#pragma unroll
          for (int nf = 0; nf < 8; ++nf) o_acc[mf][nf][r] *= fsc;
        }
      }
      float psum[4] = {0.f, 0.f, 0.f, 0.f};
#pragma unroll
      for (int nf = 0; nf < 4; ++nf)
#pragma unroll
        for (int r = 0; r < 4; ++r) {
          float p = exp2f(sacc[mf][nf][r] - m_run[mf][r]);
          psum[r] += p;
          Ps[w][mf * 16 + lg * 4 + r][nf * 16 + lc] = f2b(p);
        }
#pragma unroll
      for (int r = 0; r < 4; ++r) {
        float ps = psum[r];
        ps += __shfl_xor(ps, 1);
        ps += __shfl_xor(ps, 2);
        ps += __shfl_xor(ps, 4);
        ps += __shfl_xor(ps, 8);
        l_run[mf][r] += ps;
      }
    }
#pragma unroll
    for (int ks = 0; ks < 2; ++ks) {
      s16x8 pf[2];
#pragma unroll
      for (int mf = 0; mf < 2; ++mf)
        pf[mf] = *(const s16x8*)&Ps[w][mf * 16 + lc][ks * 32 + lg * 8];
#pragma unroll
      for (int nf = 0; nf < 8; ++nf) {
        s16x8 vf = *(const s16x8*)&Vs[nf * 16 + lc][ks * 32 + lg * 8];
#pragma unroll
        for (int mf = 0; mf < 2; ++mf)
          o_acc[mf][nf] = __builtin_amdgcn_mfma_f32_16x16x32_bf16(pf[mf], vf, o_acc[mf][nf], 0, 0, 0);
      }
    }
  }

#pragma unroll
  for (int mf = 0; mf < 2; ++mf)
#pragma unroll
    for (int r = 0; r < 4; ++r) {
      float inv = 1.0f / l_run[mf][r];
      int qg = qw + mf * 16 + lg * 4 + r;
#pragma unroll
      for (int nf = 0; nf < 8; ++nf)
        attn[(size_t)(b * 2048 + qg) * 4096 + h * 128 + nf * 16 + lc] =
            f2b(o_acc[mf][nf][r] * inv);
    }
}

extern "C" void kernel_launch(void* const* d_in, const int* in_sizes, int n_in,
                              void* d_out, int out_size, void* d_ws, size_t ws_size,
                              hipStream_t stream) {
  (void)in_sizes; (void)n_in; (void)out_size; (void)ws_size;
  const float* x = (const float*)d_in[0];
  const float* cosb = (const float*)d_in[1];
  const float* sinb = (const float*)d_in[2];
  const float* Wqkv = (const float*)d_in[3];
  const float* Wout = (const float*)d_in[4];
  float* out = (float*)d_out;
  char* ws = (char*)d_ws;

  // buf0 (50.3MB): Wqkv_t, later attn_out.  buf1 (50.3MB): qkv (roped in
  // place), later Wout_t.  v_t (8.4MB).  Total 109MB.
  u16* buf0 = (u16*)ws;
  u16* buf1 = (u16*)(ws + 50331648);
  u16* v_t  = (u16*)(ws + 100663296);

  trans_bf16<<<dim3(96, 64), 256, 0, stream>>>(Wqkv, buf0, 4096, 6144);
  gemm_kernel<true, u16><<<dim3(48, 32), 256, 0, stream>>>(x, buf0, buf1, 4096, 6144, 4096);
  rope_kernel<<<4096, 256, 0, stream>>>(buf1, cosb, sinb);
  vtrans_kernel<<<dim3(32, 2, 16), 256, 0, stream>>>(buf1, v_t);
  attn_kernel<<<1024, 256, 0, stream>>>(buf1, v_t, buf0);
  trans_bf16<<<dim3(64, 64), 256, 0, stream>>>(Wout, buf1, 4096, 4096);
  gemm_kernel<false, float><<<dim3(32, 32), 256, 0, stream>>>(buf0, buf1, out, 4096, 4096, 4096);
}

// Round 3
// 621.369 us; speedup vs baseline: 3.4175x; 1.2659x over previous
//
#include <hip/hip_runtime.h>

typedef unsigned short u16;
typedef __attribute__((ext_vector_type(8))) short s16x8;
typedef __attribute__((ext_vector_type(4))) short s16x4;
typedef __attribute__((ext_vector_type(4))) float f32x4;

#define DEVI __device__ __forceinline__

DEVI u16 f2b(float f) {
  union { float f; unsigned u; } v; v.f = f;
  unsigned r = v.u + 0x7FFFu + ((v.u >> 16) & 1u);
  return (u16)(r >> 16);
}
DEVI float b2f(u16 h) {
  union { unsigned u; float f; } v; v.u = ((unsigned)h) << 16;
  return v.f;
}

typedef const __attribute__((address_space(1))) void gas_void;
typedef __attribute__((address_space(3))) void las_void;
DEVI void gload16(const void* g, void* l) {
  __builtin_amdgcn_global_load_lds((gas_void*)g, (las_void*)l, 16, 0, 0);
}

// x f32 -> bf16 (identical rounding to in-staging convert)
__global__ void conv_bf16(const float* __restrict__ in, u16* __restrict__ out, int n8) {
  int i = blockIdx.x * 256 + threadIdx.x;
  if (i >= n8) return;
  const float* p = in + (size_t)i * 8;
  float4 u = *(const float4*)p;
  float4 v = *(const float4*)(p + 4);
  s16x8 o = {(short)f2b(u.x), (short)f2b(u.y), (short)f2b(u.z), (short)f2b(u.w),
             (short)f2b(v.x), (short)f2b(v.y), (short)f2b(v.z), (short)f2b(v.w)};
  *(s16x8*)(out + (size_t)i * 8) = o;
}

// W [K][N] f32 -> Wt [N][K] bf16 (64x64 tiles)
__global__ void trans_bf16(const float* __restrict__ W, u16* __restrict__ Wt, int K, int N) {
  __shared__ __attribute__((aligned(16))) u16 tile[64][68];
  const int t = threadIdx.x;
  const int n0 = blockIdx.x * 64, k0 = blockIdx.y * 64;
#pragma unroll
  for (int i = 0; i < 4; ++i) {
    int c = i * 256 + t;
    int r = c >> 4, q = c & 15;
    float4 v = *(const float4*)(W + (size_t)(k0 + r) * N + n0 + q * 4);
    s16x4 o = {(short)f2b(v.x), (short)f2b(v.y), (short)f2b(v.z), (short)f2b(v.w)};
    *(s16x4*)&tile[r][q * 4] = o;
  }
  __syncthreads();
#pragma unroll
  for (int i = 0; i < 2; ++i) {
    int c = i * 256 + t;
    int n_ = c >> 3, ck = (c & 7) * 8;
    s16x8 o;
#pragma unroll
    for (int j = 0; j < 8; ++j) o[j] = (short)tile[ck + j][n_];
    *(s16x8*)(Wt + (size_t)(n0 + n_) * K + k0 + ck) = o;
  }
}

// ---------------------------------------------------------------------------
// 256x256 8-phase bf16 GEMM: C[M][N] = A[M][K] @ Bt[N][K]^T.
// 512 thr / 8 waves (2Mx4N); BK=64; LDS 128KiB dbuf; global_load_lds w=16 with
// slot^(row&7) source pre-swizzle; per K-tile 4 phases, raw s_barrier pairs,
// vmcnt(0) only at phase 3 (loads issued phases 0-1 -> ~counted); setprio
// around the 16-MFMA cluster. XCD-bijective block swizzle (grids %8==0).
// ---------------------------------------------------------------------------
template <typename TC>
__global__ __launch_bounds__(512, 2) void gemm256(const u16* __restrict__ A,
                                                  const u16* __restrict__ Bt,
                                                  TC* __restrict__ C, int M, int N, int K) {
  __shared__ __attribute__((aligned(16))) u16 As[2][256 * 64];
  __shared__ __attribute__((aligned(16))) u16 Bs[2][256 * 64];
  const int t = threadIdx.x;
  const int nbn = N >> 8;
  const int nwg = (M >> 8) * nbn;
  const int chunk = nwg >> 3;
  const int id = (blockIdx.x & 7) * chunk + (blockIdx.x >> 3);
  const int row0 = (id / nbn) << 8, col0 = (id % nbn) << 8;
  const int w = t >> 6, lane = t & 63, lc = lane & 15, lg = lane >> 4;
  const int wm = (w >> 2) * 128, wn = (w & 3) * 64;
  const int sw7 = lc & 7;  // row&7 for all fragment rows this lane touches

  const f32x4 FZ = {0.f, 0.f, 0.f, 0.f};
  f32x4 acc[8][4];
#pragma unroll
  for (int i = 0; i < 8; ++i)
#pragma unroll
    for (int j = 0; j < 4; ++j) acc[i][j] = FZ;

  // staging chunk c = i*512+t : row=c>>3 (0..255), phys slot=c&7;
  // source k-slot = phys ^ (row&7)  (involution; read applies same XOR)
  const int c_r[4] = {(0 * 512 + t) >> 3, (1 * 512 + t) >> 3, (2 * 512 + t) >> 3, (3 * 512 + t) >> 3};
  const int c_s[4] = {t & 7, t & 7, t & 7, t & 7};  // (i*512+t)&7 == t&7

#define ISSUE_A(i, kt, slot)                                                              \
  gload16(A + (size_t)(row0 + c_r[i]) * K + ((kt) << 6) + ((c_s[i] ^ (c_r[i] & 7)) << 3), \
          (u16*)As[slot] + ((i) * 512 + t) * 8)
#define ISSUE_B(i, kt, slot)                                                              \
  gload16(Bt + (size_t)(col0 + c_r[i]) * K + ((kt) << 6) + ((c_s[i] ^ (c_r[i] & 7)) << 3), \
          (u16*)Bs[slot] + ((i) * 512 + t) * 8)

  const int NT = K >> 6;
  // prologue: tile 0
  ISSUE_A(0, 0, 0); ISSUE_B(0, 0, 0); ISSUE_A(1, 0, 0); ISSUE_B(1, 0, 0);
  ISSUE_A(2, 0, 0); ISSUE_B(2, 0, 0); ISSUE_A(3, 0, 0); ISSUE_B(3, 0, 0);
  asm volatile("s_waitcnt vmcnt(0)" ::: "memory");
  __builtin_amdgcn_s_barrier();

  for (int kt = 0; kt < NT; ++kt) {
    const int cur = kt & 1, nxt = cur ^ 1;
    const bool pf = (kt + 1 < NT);
    const u16* Ac = As[cur];
    const u16* Bc = Bs[cur];
#pragma unroll
    for (int q = 0; q < 4; ++q) {
      const int mh = q >> 1, nh = q & 1;
      s16x8 af[4][2], bfv[2][2];
#pragma unroll
      for (int mf = 0; mf < 4; ++mf) {
        const int r = wm + mh * 64 + mf * 16 + lc;
#pragma unroll
        for (int ks = 0; ks < 2; ++ks) {
          const int g = ks * 4 + lg;
          af[mf][ks] = *(const s16x8*)(Ac + r * 64 + ((g ^ sw7) << 3));
        }
      }
#pragma unroll
      for (int nf = 0; nf < 2; ++nf) {
        const int r = wn + nh * 32 + nf * 16 + lc;
#pragma unroll
        for (int ks = 0; ks < 2; ++ks) {
          const int g = ks * 4 + lg;
          bfv[nf][ks] = *(const s16x8*)(Bc + r * 64 + ((g ^ sw7) << 3));
        }
      }
      if (q == 0 && pf) { ISSUE_A(0, kt + 1, nxt); ISSUE_B(0, kt + 1, nxt); ISSUE_A(1, kt + 1, nxt); ISSUE_B(1, kt + 1, nxt); }
      if (q == 1 && pf) { ISSUE_A(2, kt + 1, nxt); ISSUE_B(2, kt + 1, nxt); ISSUE_A(3, kt + 1, nxt); ISSUE_B(3, kt + 1, nxt); }
      if (q == 3) asm volatile("s_waitcnt vmcnt(0)" ::: "memory");
      __builtin_amdgcn_s_barrier();
      __builtin_amdgcn_s_setprio(1);
#pragma unroll
      for (int ks = 0; ks < 2; ++ks)
#pragma unroll
        for (int mf = 0; mf < 4; ++mf)
#pragma unroll
          for (int nf = 0; nf < 2; ++nf)
            acc[mh * 4 + mf][nh * 2 + nf] = __builtin_amdgcn_mfma_f32_16x16x32_bf16(
                af[mf][ks], bfv[nf][ks], acc[mh * 4 + mf][nh * 2 + nf], 0, 0, 0);
      __builtin_amdgcn_s_setprio(0);
      __builtin_amdgcn_s_barrier();
    }
  }
#undef ISSUE_A
#undef ISSUE_B

#pragma unroll
  for (int am = 0; am < 8; ++am)
#pragma unroll
    for (int an = 0; an < 4; ++an)
#pragma unroll
      for (int r = 0; r < 4; ++r) {
        const int rg = row0 + wm + (am >> 2) * 64 + (am & 3) * 16 + lg * 4 + r;
        const int cg = col0 + wn + (an >> 1) * 32 + (an & 1) * 16 + lc;
        if constexpr (sizeof(TC) == 2)
          ((u16*)C)[(size_t)rg * N + cg] = f2b(acc[am][an][r]);
        else
          ((float*)C)[(size_t)rg * N + cg] = acc[am][an][r];
      }
}

// In-place RoPE on qkv columns [0, 5120): q heads 0..31, k heads 32..39.
__global__ void rope_kernel(u16* __restrict__ qkv, const float* __restrict__ cosb,
                            const float* __restrict__ sinb) {
  const int bs = blockIdx.x;
  const int s = bs & 2047;
  u16* row = qkv + (size_t)bs * 6144;
  const float* cr = cosb + s * 128;
  const float* sr = sinb + s * 128;
  for (int p = threadIdx.x; p < 320; p += 256) {
    int head = p >> 3, dc = (p & 7) * 8;
    int ci = head * 128 + dc;
    s16x8 a = *(const s16x8*)&row[ci];
    s16x8 bb = *(const s16x8*)&row[ci + 64];
    float4 c0 = *(const float4*)(cr + dc), c1 = *(const float4*)(cr + dc + 4);
    float4 s0 = *(const float4*)(sr + dc), s1 = *(const float4*)(sr + dc + 4);
    float cv[8] = {c0.x, c0.y, c0.z, c0.w, c1.x, c1.y, c1.z, c1.w};
    float sv[8] = {s0.x, s0.y, s0.z, s0.w, s1.x, s1.y, s1.z, s1.w};
    s16x8 o1, o2;
#pragma unroll
    for (int j = 0; j < 8; ++j) {
      float x1 = b2f((u16)a[j]), x2 = b2f((u16)bb[j]);
      o1[j] = (short)f2b(x1 * cv[j] - x2 * sv[j]);
      o2[j] = (short)f2b(x2 * cv[j] + x1 * sv[j]);
    }
    *(s16x8*)&row[ci] = o1;
    *(s16x8*)&row[ci + 64] = o2;
  }
}

// v_t[b][kvh][d][s] = qkv[b][s][5120 + kvh*128 + d]
__global__ void vtrans_kernel(const u16* __restrict__ qkv, u16* __restrict__ v_t) {
  __shared__ __attribute__((aligned(16))) u16 tile[64][72];
  const int t = threadIdx.x;
  const int s0 = blockIdx.x * 64;
  const int d0 = blockIdx.y * 64;
  const int bk = blockIdx.z;
  const int b = bk >> 3, kvh = bk & 7;
  const int slot = t & 7, r0 = t >> 3;
#pragma unroll
  for (int i = 0; i < 2; ++i) {
    int s_ = r0 + 32 * i;
    *(s16x8*)&tile[s_][slot * 8] =
        *(const s16x8*)(qkv + (size_t)(b * 2048 + s0 + s_) * 6144 + 5120 + kvh * 128 + d0 + slot * 8);
  }
  __syncthreads();
#pragma unroll
  for (int i = 0; i < 2; ++i) {
    int d_ = r0 + 32 * i;
    s16x8 v;
#pragma unroll
    for (int j = 0; j < 8; ++j) v[j] = (short)tile[slot * 8 + j][d_];
    *(s16x8*)(v_t + ((size_t)bk * 128 + d0 + d_) * 2048 + s0 + slot * 8) = v;
  }
}

// Flash causal attention; Q/K read from roped qkv; V from v_t.
// Grid = 1024 (1D), XCD-grouped, largest q-tile first, T14 register prefetch.
__global__ void __launch_bounds__(256, 2) attn_kernel(const u16* __restrict__ qkv,
                                                      const u16* __restrict__ v_t,
                                                      u16* __restrict__ attn) {
  __shared__ __attribute__((aligned(16))) u16 Ks[64][136];
  __shared__ __attribute__((aligned(16))) u16 Vs[128][72];
  __shared__ __attribute__((aligned(16))) u16 Ps[4][32][72];
  const int t = threadIdx.x;
  const int f = blockIdx.x;
  const int xcd = f & 7, ix = f >> 3;
  const int g = (xcd << 1) | (ix >> 6);
  const int r_ = ix & 63;
  const int b = g >> 3, kvh = g & 7;
  const int qt = 15 - (r_ >> 2);
  const int h = kvh * 4 + (r_ & 3);
  const int q0 = qt * 128;
  const int w = t >> 6, lane = t & 63, lc = lane & 15, lg = lane >> 4;
  const int qw = q0 + w * 32;

  const u16* qbase = qkv + (size_t)(b * 2048) * 6144 + h * 128;
  const u16* kbase = qkv + (size_t)(b * 2048) * 6144 + 4096 + kvh * 128;
  const u16* vbase = v_t + (size_t)(b * 8 + kvh) * 128 * 2048;

  s16x8 qf[2][4];
#pragma unroll
  for (int mf = 0; mf < 2; ++mf)
#pragma unroll
    for (int ks = 0; ks < 4; ++ks)
      qf[mf][ks] = *(const s16x8*)(qbase + (size_t)(qw + mf * 16 + lc) * 6144 + ks * 32 + lg * 8);

  const f32x4 FZ = {0.f, 0.f, 0.f, 0.f};
  f32x4 o_acc[2][8];
  float m_run[2][4], l_run[2][4];
#pragma unroll
  for (int mf = 0; mf < 2; ++mf) {
#pragma unroll
    for (int nf = 0; nf < 8; ++nf) o_acc[mf][nf] = FZ;
#pragma unroll
    for (int r = 0; r < 4; ++r) { m_run[mf][r] = -3e38f; l_run[mf][r] = 0.f; }
  }
  const float scale2 = 0.08838834764831845f * 1.44269504088896340736f;

  const int ntiles = q0 / 64 + 2;
  s16x8 kr[4], vr[4];
#pragma unroll
  for (int i = 0; i < 4; ++i) {
    int c = i * 256 + t;
    kr[i] = *(const s16x8*)(kbase + (size_t)(c >> 4) * 6144 + (c & 15) * 8);
    vr[i] = *(const s16x8*)(vbase + (size_t)(c >> 3) * 2048 + (c & 7) * 8);
  }

  for (int kt = 0; kt < ntiles; ++kt) {
    const int k0 = kt * 64;
    __syncthreads();
#pragma unroll
    for (int i = 0; i < 4; ++i) {
      int c = i * 256 + t;
      *(s16x8*)&Ks[c >> 4][(c & 15) * 8] = kr[i];
      *(s16x8*)&Vs[c >> 3][(c & 7) * 8] = vr[i];
    }
    __syncthreads();
    if (kt + 1 < ntiles) {
      int k1 = k0 + 64;
#pragma unroll
      for (int i = 0; i < 4; ++i) {
        int c = i * 256 + t;
        kr[i] = *(const s16x8*)(kbase + (size_t)(k1 + (c >> 4)) * 6144 + (c & 15) * 8);
        vr[i] = *(const s16x8*)(vbase + (size_t)(c >> 3) * 2048 + k1 + (c & 7) * 8);
      }
    }
    if (k0 > qw + 31) continue;

    f32x4 sacc[2][4];
#pragma unroll
    for (int mf = 0; mf < 2; ++mf)
#pragma unroll
      for (int nf = 0; nf < 4; ++nf) sacc[mf][nf] = FZ;
#pragma unroll
    for (int ks = 0; ks < 4; ++ks) {
      s16x8 kf[4];
#pragma unroll
      for (int nf = 0; nf < 4; ++nf)
        kf[nf] = *(const s16x8*)&Ks[nf * 16 + lc][ks * 32 + lg * 8];
#pragma unroll
      for (int mf = 0; mf < 2; ++mf)
#pragma unroll
        for (int nf = 0; nf < 4; ++nf)
          sacc[mf][nf] = __builtin_amdgcn_mfma_f32_16x16x32_bf16(qf[mf][ks], kf[nf], sacc[mf][nf], 0, 0, 0);
    }

#pragma unroll
    for (int mf = 0; mf < 2; ++mf) {
      float pm[4] = {-3e38f, -3e38f, -3e38f, -3e38f};
      const bool dm = (k0 + 63 > qw + mf * 16);
      if (dm) {
#pragma unroll
        for (int nf = 0; nf < 4; ++nf) {
          int kv = k0 + nf * 16 + lc;
#pragma unroll
          for (int r = 0; r < 4; ++r) {
            int qg = qw + mf * 16 + lg * 4 + r;
            float sv = sacc[mf][nf][r] * scale2;
            sv = (kv <= qg) ? sv : -3e38f;
            sacc[mf][nf][r] = sv;
            pm[r] = fmaxf(pm[r], sv);
          }
        }
      } else {
#pragma unroll
        for (int nf = 0; nf < 4; ++nf)
#pragma unroll
          for (int r = 0; r < 4; ++r) {
            float sv = sacc[mf][nf][r] * scale2;
            sacc[mf][nf][r] = sv;
            pm[r] = fmaxf(pm[r], sv);
          }
      }
#pragma unroll
      for (int r = 0; r < 4; ++r) {
        pm[r] = fmaxf(pm[r], __shfl_xor(pm[r], 1));
        pm[r] = fmaxf(pm[r], __shfl_xor(pm[r], 2));
        pm[r] = fmaxf(pm[r], __shfl_xor(pm[r], 4));
        pm[r] = fmaxf(pm[r], __shfl_xor(pm[r], 8));
      }
      bool any = false;
      float mnew[4];
#pragma unroll
      for (int r = 0; r < 4; ++r) {
        mnew[r] = fmaxf(m_run[mf][r], pm[r]);
        any |= (mnew[r] > m_run[mf][r]);
      }
      if (__any(any)) {
#pragma unroll
        for (int r = 0; r < 4; ++r) {
          float fsc = exp2f(m_run[mf][r] - mnew[r]);
          m_run[mf][r] = mnew[r];
          l_run[mf][r] *= fsc;
#pragma unroll
          for (int nf = 0; nf < 8; ++nf) o_acc[mf][nf][r] *= fsc;
        }
      }
      float psum[4] = {0.f, 0.f, 0.f, 0.f};
#pragma unroll
      for (int nf = 0; nf < 4; ++nf)
#pragma unroll
        for (int r = 0; r < 4; ++r) {
          float p = exp2f(sacc[mf][nf][r] - m_run[mf][r]);
          psum[r] += p;
          Ps[w][mf * 16 + lg * 4 + r][nf * 16 + lc] = f2b(p);
        }
#pragma unroll
      for (int r = 0; r < 4; ++r) {
        float ps = psum[r];
        ps += __shfl_xor(ps, 1);
        ps += __shfl_xor(ps, 2);
        ps += __shfl_xor(ps, 4);
        ps += __shfl_xor(ps, 8);
        l_run[mf][r] += ps;
      }
    }
#pragma unroll
    for (int ks = 0; ks < 2; ++ks) {
      s16x8 pf[2];
#pragma unroll
      for (int mf = 0; mf < 2; ++mf)
        pf[mf] = *(const s16x8*)&Ps[w][mf * 16 + lc][ks * 32 + lg * 8];
#pragma unroll
      for (int nf = 0; nf < 8; ++nf) {
        s16x8 vf = *(const s16x8*)&Vs[nf * 16 + lc][ks * 32 + lg * 8];
#pragma unroll
        for (int mf = 0; mf < 2; ++mf)
          o_acc[mf][nf] = __builtin_amdgcn_mfma_f32_16x16x32_bf16(pf[mf], vf, o_acc[mf][nf], 0, 0, 0);
      }
    }
  }

#pragma unroll
  for (int mf = 0; mf < 2; ++mf)
#pragma unroll
    for (int r = 0; r < 4; ++r) {
      float inv = 1.0f / l_run[mf][r];
      int qg = qw + mf * 16 + lg * 4 + r;
#pragma unroll
      for (int nf = 0; nf < 8; ++nf)
        attn[(size_t)(b * 2048 + qg) * 4096 + h * 128 + nf * 16 + lc] =
            f2b(o_acc[mf][nf][r] * inv);
    }
}

extern "C" void kernel_launch(void* const* d_in, const int* in_sizes, int n_in,
                              void* d_out, int out_size, void* d_ws, size_t ws_size,
                              hipStream_t stream) {
  (void)in_sizes; (void)n_in; (void)out_size; (void)ws_size;
  const float* x = (const float*)d_in[0];
  const float* cosb = (const float*)d_in[1];
  const float* sinb = (const float*)d_in[2];
  const float* Wqkv = (const float*)d_in[3];
  const float* Wout = (const float*)d_in[4];
  float* out = (float*)d_out;
  char* ws = (char*)d_ws;

  // [0..50.3MB)   buf0: Wqkv_t, later attn_out
  // [50.3..100.7) buf1: qkv (roped in place)
  // [100.7..128M) region C: xb (33.6MB) -> later v_t (8.4MB) -> later Wout_t (33.6MB)
  u16* buf0 = (u16*)ws;
  u16* buf1 = (u16*)(ws + 50331648);
  u16* regc = (u16*)(ws + 100663296);

  conv_bf16<<<8192, 256, 0, stream>>>(x, regc, 2097152);                      // xb
  trans_bf16<<<dim3(96, 64), 256, 0, stream>>>(Wqkv, buf0, 4096, 6144);       // Wqkv_t
  gemm256<u16><<<384, 512, 0, stream>>>(regc, buf0, buf1, 4096, 6144, 4096);  // qkv
  rope_kernel<<<4096, 256, 0, stream>>>(buf1, cosb, sinb);
  vtrans_kernel<<<dim3(32, 2, 16), 256, 0, stream>>>(buf1, regc);             // v_t (over xb)
  attn_kernel<<<1024, 256, 0, stream>>>(buf1, regc, buf0);                    // attn_out (over Wqkv_t)
  trans_bf16<<<dim3(64, 64), 256, 0, stream>>>(Wout, regc, 4096, 4096);       // Wout_t (over v_t)
  gemm256<float><<<256, 512, 0, stream>>>(buf0, regc, out, 4096, 4096, 4096); // out
}